// Round 13
// baseline (82.526 us; speedup 1.0000x reference)
//
#include <hip/hip_runtime.h>
#include <hip/hip_bf16.h>
#include <hip/hip_fp16.h>
#include <math.h>
#include <stdint.h>

constexpr int Nn = 4096, Kk = 32, Hh = 256;
constexpr int Mm = 8 * Nn;          // 32768 rows

typedef float  f32x4 __attribute__((ext_vector_type(4)));
typedef short  s16x8 __attribute__((ext_vector_type(8)));
struct alignas(16) H2x4 { __half2 a, b, c, d; };   // 8 halfs = 16 B

static __device__ __forceinline__ ushort f2bf(float f) {
  uint32_t u = __float_as_uint(f);
  u += 0x7FFF + ((u >> 16) & 1);
  return (ushort)(u >> 16);
}
static __device__ __forceinline__ void gl_lds16(const ushort* g, ushort* l) {
  __builtin_amdgcn_global_load_lds(
      (const __attribute__((address_space(1))) void*)g,
      (__attribute__((address_space(3))) void*)l, 16, 0, 0);
}
// gelu(x) ~= x - x/(e^y + 1),  y = x*(2c + 2c*0.044715*x^2), c = 0.79788456
static __device__ __forceinline__ float gelu_t(float x) {
  float u = x * x;
  float y = x * (1.5957691216f + 0.0713548162726f * u);
  float t = __expf(y);
  return x - x * __builtin_amdgcn_rcpf(t + 1.0f);
}

// ------- prep: Wcat = [Ws; Wn] bf16 [512][256]; also idx-dtype detect ------
__global__ __launch_bounds__(256) void prep_w(const float* __restrict__ Ws,
                                              const float* __restrict__ Wn,
                                              ushort* __restrict__ Wc,
                                              const int* __restrict__ idxp,
                                              int* __restrict__ flag) {
  if (blockIdx.x == 0 && threadIdx.x < 64) {   // wave 0: int64 high-word test
    unsigned long long bl = __ballot(idxp[2 * threadIdx.x + 1] != 0);
    if (threadIdx.x == 0) *flag = (bl != 0ULL) ? 1 : 0;  // 1=int32, 0=int64
  }
  int i = blockIdx.x * 256 + threadIdx.x;      // 32768 threads, 4 elems each
  int j  = i >> 6;
  int k4 = i & 63;
  const float* src = (j < 256) ? (Ws + (size_t)j * 256 + k4 * 4)
                               : (Wn + (size_t)(j - 256) * 256 + k4 * 4);
  float4 v = *reinterpret_cast<const float4*>(src);
  ushort4 o = { f2bf(v.x), f2bf(v.y), f2bf(v.z), f2bf(v.w) };
  reinterpret_cast<ushort4*>(Wc)[i] = o;
}

// ------- prep_meta: meta[b][k][t] = (u16 row) | (fp16 w)<<16, k-major ------
// Thread per (b,t): contiguous per-lane reads; k-step writes are 4B x 64
// consecutive t = 256B coalesced per wave.
__global__ __launch_bounds__(256) void prep_meta(const void* __restrict__ idx,
                                                 const float* __restrict__ w,
                                                 uint* __restrict__ meta,
                                                 const int* __restrict__ flag) {
  int i = blockIdx.x * 256 + threadIdx.x;      // i = b*4096 + t
  int b = i >> 12, t = i & 4095;
  int is32 = *flag;
  const int*       i32 = (const int*)idx + (size_t)i * Kk;
  const long long* i64 = (const long long*)idx + (size_t)i * Kk;
  const float*     wp  = w + (size_t)i * Kk;
  uint* mb = meta + ((size_t)b << 17);         // 32*4096 per batch
  #pragma unroll
  for (int k = 0; k < Kk; ++k) {
    uint r = (uint)(is32 ? i32[k] : (int)i64[k]) & 0xFFFFu;
    ushort hw = __half_as_ushort(__float2half(wp[k]));
    mb[(size_t)k * 4096 + t] = r | ((uint)hw << 16);
  }
}

// ---------------- gemm1: [hs|hn] = h @ Wcat^T, fp16 out (R12-proven) -------
__global__ __launch_bounds__(512, 4) void gemm1(const float* __restrict__ h,
                                                const ushort* __restrict__ Wc,
                                                __half* __restrict__ hs,
                                                __half* __restrict__ hn) {
  __shared__ ushort lA[2][64 * 64];    // 2 x 8 KB
  __shared__ ushort lB[2][256 * 64];   // 2 x 32 KB
  const int tid = threadIdx.x, wid = tid >> 6, lane = tid & 63;
  const int wr = wid >> 1, wc = wid & 1;

  const int blk = blockIdx.x;
  const int b = blk & 7, t = blk >> 3;
  const int nblk = t & 1, mblk = t >> 1;
  const int m0 = b * Nn + mblk * 64;
  const ushort* Wbase = Wc + (size_t)nblk * 256 * 256;

  f32x4 acc[8];
  #pragma unroll
  for (int j = 0; j < 8; ++j) acc[j] = f32x4{0.f, 0.f, 0.f, 0.f};

  float4 a0, a1;
  const int ar = tid >> 3, as = tid & 7;             // A stage: row, slot
  auto aload = [&](int kt) {
    const float* src = h + (size_t)(m0 + ar) * 256 + kt * 64 + as * 8;
    a0 = *reinterpret_cast<const float4*>(src);
    a1 = *reinterpret_cast<const float4*>(src + 4);
  };
  auto awrite = [&](int buf) {
    s16x8 u = { (short)f2bf(a0.x), (short)f2bf(a0.y), (short)f2bf(a0.z),
                (short)f2bf(a0.w), (short)f2bf(a1.x), (short)f2bf(a1.y),
                (short)f2bf(a1.z), (short)f2bf(a1.w) };
    *reinterpret_cast<s16x8*>(&lA[buf][ar * 64 + ((as ^ (ar & 7)) << 3)]) = u;
  };
  auto bstage = [&](int buf, int kt) {
    #pragma unroll
    for (int c = 0; c < 4; ++c) {
      int ch = wid + c * 8;
      int r = ch * 8 + (lane >> 3);
      int s = (lane & 7) ^ (r & 7);
      gl_lds16(Wbase + (size_t)r * 256 + kt * 64 + s * 8, &lB[buf][ch * 512]);
    }
  };

  aload(0);
  bstage(0, 0);
  awrite(0);
  __syncthreads();

  int buf = 0;
  for (int kt = 0; kt < 4; ++kt) {
    if (kt < 3) { aload(kt + 1); bstage(buf ^ 1, kt + 1); }
    #pragma unroll
    for (int kk = 0; kk < 2; ++kk) {
      const int ks = kk * 4 + (lane >> 4);
      const int ra = wr * 16 + (lane & 15);
      s16x8 af = *reinterpret_cast<const s16x8*>(
          &lA[buf][ra * 64 + ((ks ^ (ra & 7)) << 3)]);
      s16x8 bfr[8];
      #pragma unroll
      for (int nj = 0; nj < 8; ++nj) {
        int rb = wc * 128 + nj * 16 + (lane & 15);
        bfr[nj] = *reinterpret_cast<const s16x8*>(
            &lB[buf][rb * 64 + ((ks ^ (rb & 7)) << 3)]);
      }
      #pragma unroll
      for (int nj = 0; nj < 8; ++nj)
        acc[nj] = __builtin_amdgcn_mfma_f32_16x16x32_bf16(af, bfr[nj],
                                                          acc[nj], 0, 0, 0);
    }
    if (kt < 3) awrite(buf ^ 1);
    __syncthreads();
    buf ^= 1;
  }

  __half* dst = (nblk == 0) ? hs : hn;
  #pragma unroll
  for (int nj = 0; nj < 8; ++nj)
    #pragma unroll
    for (int jj = 0; jj < 4; ++jj) {
      int row = wr * 16 + (lane >> 4) * 4 + jj;
      int col = wc * 128 + nj * 16 + (lane & 15);
      dst[(size_t)(m0 + row) * 256 + col] = __float2half(acc[nj][jj]);
    }
}

// ---------------- k2a: LDS-staged slice gather ----------------
// Block = (batch b, slice c of 8 fp16 cols). Stage hn[b][all 4096 rows][c*8..
// c*8+8) (16B/row) into 64KB LDS via global_load_lds (per-lane strided global
// src, wave-uniform linear LDS dest). Then lane t gathers its target row's 32
// neighbors from LDS (ds_read_b128 at random rows; bank group = r&7 spreads).
// Writes h_agg slice IN-PLACE over hn (each 16B staged by this block first).
__global__ __launch_bounds__(512, 1) void k2a(__half* __restrict__ hn,
                                              const uint* __restrict__ meta) {
  __shared__ __align__(16) __half sl[4096 * 8];   // 64 KB
  const int tid = threadIdx.x, wv = tid >> 6, lane = tid & 63;
  const int b = blockIdx.x & 7;                   // batch -> XCD-ish
  const int c = blockIdx.x >> 3;                  // slice 0..31
  __half* hnb = hn + ((size_t)b << 20);           // b*4096*256

  // stage: 8 iters x 512 threads, 16B per lane, linear LDS
  #pragma unroll
  for (int j = 0; j < 8; ++j) {
    int rbase = j * 512 + wv * 64;                // wave-uniform
    gl_lds16((const ushort*)(hnb + (size_t)(rbase + lane) * 256 + c * 8),
             (ushort*)&sl[rbase * 8]);
  }
  __syncthreads();                                // drains global_load_lds

  const uint* mb = meta + ((size_t)b << 17);

  // each wave: 512 targets in 8 chunks of 64 (lane = target)
  for (int ch = 0; ch < 8; ++ch) {
    const int t = wv * 512 + ch * 64 + lane;
    const uint* mcol = mb + t;

    uint mk[32];                                  // all metadata upfront
    #pragma unroll
    for (int k = 0; k < 32; ++k) mk[k] = mcol[(size_t)k << 12];

    f32x4 aA0{0,0,0,0}, aA1{0,0,0,0}, aB0{0,0,0,0}, aB1{0,0,0,0};

#define DS(k) (*reinterpret_cast<const H2x4*>(&sl[(mk[k] & 0xFFFFu) * 8]))
#define WVAL(k) __half2float(__ushort_as_half((ushort)(mk[k] >> 16)))
#define CONS(b0, b1, q, wt) { \
    b0[0] += (float)q.a.x * wt; b0[1] += (float)q.a.y * wt; \
    b0[2] += (float)q.b.x * wt; b0[3] += (float)q.b.y * wt; \
    b1[0] += (float)q.c.x * wt; b1[1] += (float)q.c.y * wt; \
    b1[2] += (float)q.d.x * wt; b1[3] += (float)q.d.y * wt; }

    H2x4 p0 = DS(0), p1 = DS(1), p2 = DS(2), p3 = DS(3);
    #pragma unroll
    for (int k = 0; k < 32; k += 4) {
      float w0 = WVAL(k), w1 = WVAL(k + 1), w2 = WVAL(k + 2), w3 = WVAL(k + 3);
      H2x4 q0 = p0, q1 = p1, q2 = p2, q3 = p3;
      if (k + 4 < 32) {
        p0 = DS(k + 4); p1 = DS(k + 5); p2 = DS(k + 6); p3 = DS(k + 7);
      }
      CONS(aA0, aA1, q0, w0); CONS(aB0, aB1, q1, w1);
      CONS(aA0, aA1, q2, w2); CONS(aB0, aB1, q3, w3);
    }
#undef DS
#undef WVAL
#undef CONS

    H2x4 o;
    o.a = __floats2half2_rn(aA0[0] + aB0[0], aA0[1] + aB0[1]);
    o.b = __floats2half2_rn(aA0[2] + aB0[2], aA0[3] + aB0[3]);
    o.c = __floats2half2_rn(aA1[0] + aB1[0], aA1[1] + aB1[1]);
    o.d = __floats2half2_rn(aA1[2] + aB1[2], aA1[3] + aB1[3]);
    *reinterpret_cast<H2x4*>(hnb + (size_t)t * 256 + c * 8) = o;  // in-place
  }
}

// ---------------- k2b: out = LN(gelu(hs[m] + hagg[m])) — pure streaming ----
__global__ __launch_bounds__(256) void k2b(const __half* __restrict__ hs,
                                           const __half* __restrict__ hagg,
                                           const float* __restrict__ gamma,
                                           const float* __restrict__ beta,
                                           float* __restrict__ out) {
  const int tid = threadIdx.x, l5 = tid & 31;
  const int m = blockIdx.x * 8 + (tid >> 5);

  H2x4 av = *reinterpret_cast<const H2x4*>(hagg + (size_t)m * Hh + l5 * 8);
  H2x4 sv_ = *reinterpret_cast<const H2x4*>(hs + (size_t)m * Hh + l5 * 8);
  float4 gm0 = reinterpret_cast<const float4*>(gamma)[l5 * 2];
  float4 gm1 = reinterpret_cast<const float4*>(gamma)[l5 * 2 + 1];
  float4 bt0 = reinterpret_cast<const float4*>(beta)[l5 * 2];
  float4 bt1 = reinterpret_cast<const float4*>(beta)[l5 * 2 + 1];

  float g[8];
  g[0] = gelu_t((float)av.a.x + (float)sv_.a.x);
  g[1] = gelu_t((float)av.a.y + (float)sv_.a.y);
  g[2] = gelu_t((float)av.b.x + (float)sv_.b.x);
  g[3] = gelu_t((float)av.b.y + (float)sv_.b.y);
  g[4] = gelu_t((float)av.c.x + (float)sv_.c.x);
  g[5] = gelu_t((float)av.c.y + (float)sv_.c.y);
  g[6] = gelu_t((float)av.d.x + (float)sv_.d.x);
  g[7] = gelu_t((float)av.d.y + (float)sv_.d.y);

  float sv = 0.f, qv = 0.f;
  #pragma unroll
  for (int j = 0; j < 8; ++j) { sv += g[j]; qv += g[j] * g[j]; }
  #pragma unroll
  for (int msk = 16; msk >= 1; msk >>= 1) {   // reduce within 32-lane half
    sv += __shfl_xor(sv, msk, 64);
    qv += __shfl_xor(qv, msk, 64);
  }
  float mean = sv * (1.0f / 256.0f);
  float var  = qv * (1.0f / 256.0f) - mean * mean;
  float inv  = rsqrtf(var + 1e-5f);

  float4 o0, o1;
  o0.x = (g[0] - mean) * inv * gm0.x + bt0.x;
  o0.y = (g[1] - mean) * inv * gm0.y + bt0.y;
  o0.z = (g[2] - mean) * inv * gm0.z + bt0.z;
  o0.w = (g[3] - mean) * inv * gm0.w + bt0.w;
  o1.x = (g[4] - mean) * inv * gm1.x + bt1.x;
  o1.y = (g[5] - mean) * inv * gm1.y + bt1.y;
  o1.z = (g[6] - mean) * inv * gm1.z + bt1.z;
  o1.w = (g[7] - mean) * inv * gm1.w + bt1.w;
  float4* op = reinterpret_cast<float4*>(out + (size_t)m * Hh + l5 * 8);
  op[0] = o0;
  op[1] = o1;
}

extern "C" void kernel_launch(void* const* d_in, const int* in_sizes, int n_in,
                              void* d_out, int out_size, void* d_ws, size_t ws_size,
                              hipStream_t stream) {
  const float* h     = (const float*)d_in[0];
  const void*  idx   = d_in[1];
  const float* w     = (const float*)d_in[2];
  const float* Ws    = (const float*)d_in[3];
  const float* Wn    = (const float*)d_in[4];
  const float* gamma = (const float*)d_in[5];
  const float* beta  = (const float*)d_in[6];
  float* out = (float*)d_out;

  __half* hs = (__half*)d_ws;                       // 16 MB
  __half* hn = hs + (size_t)Mm * Hh;                // 16 MB (becomes hagg)
  ushort* Wc = (ushort*)(hn + (size_t)Mm * Hh);     // 256 KB
  int* flag  = (int*)(Wc + 512 * 256);
  uint* meta = (uint*)(flag + 64);                  // 4 MB

  prep_w<<<128, 256, 0, stream>>>(Ws, Wn, Wc, (const int*)idx, flag);
  prep_meta<<<128, 256, 0, stream>>>(idx, w, meta, flag);
  gemm1<<<1024, 512, 0, stream>>>(h, Wc, hs, hn);
  k2a<<<256, 512, 0, stream>>>(hn, meta);
  k2b<<<4096, 256, 0, stream>>>(hs, hn, gamma, beta, out);
}

// Round 14
// 80.659 us; speedup vs baseline: 1.0231x; 1.0231x over previous
//
#include <hip/hip_runtime.h>
#include <hip/hip_bf16.h>
#include <hip/hip_fp16.h>
#include <math.h>
#include <stdint.h>

constexpr int Nn = 4096, Kk = 32, Hh = 256;
constexpr int Mm = 8 * Nn;          // 32768 rows

typedef float  f32x4 __attribute__((ext_vector_type(4)));
typedef short  s16x8 __attribute__((ext_vector_type(8)));
struct alignas(16) H2x4 { __half2 a, b, c, d; };   // 8 halfs = 16 B

static __device__ __forceinline__ ushort f2bf(float f) {
  uint32_t u = __float_as_uint(f);
  u += 0x7FFF + ((u >> 16) & 1);
  return (ushort)(u >> 16);
}
static __device__ __forceinline__ void gl_lds16(const ushort* g, ushort* l) {
  __builtin_amdgcn_global_load_lds(
      (const __attribute__((address_space(1))) void*)g,
      (__attribute__((address_space(3))) void*)l, 16, 0, 0);
}
// gelu(x) ~= x - x/(e^y + 1),  y = x*(2c + 2c*0.044715*x^2), c = 0.79788456
static __device__ __forceinline__ float gelu_t(float x) {
  float u = x * x;
  float y = x * (1.5957691216f + 0.0713548162726f * u);
  float t = __expf(y);
  return x - x * __builtin_amdgcn_rcpf(t + 1.0f);
}

// ------- prep: Wcat = [Ws; Wn] bf16 [512][256]; also idx-dtype detect ------
__global__ __launch_bounds__(256) void prep_w(const float* __restrict__ Ws,
                                              const float* __restrict__ Wn,
                                              ushort* __restrict__ Wc,
                                              const int* __restrict__ idxp,
                                              int* __restrict__ flag) {
  if (blockIdx.x == 0 && threadIdx.x < 64) {   // wave 0: int64 high-word test
    unsigned long long bl = __ballot(idxp[2 * threadIdx.x + 1] != 0);
    if (threadIdx.x == 0) *flag = (bl != 0ULL) ? 1 : 0;  // 1=int32, 0=int64
  }
  int i = blockIdx.x * 256 + threadIdx.x;      // 32768 threads, 4 elems each
  int j  = i >> 6;
  int k4 = i & 63;
  const float* src = (j < 256) ? (Ws + (size_t)j * 256 + k4 * 4)
                               : (Wn + (size_t)(j - 256) * 256 + k4 * 4);
  float4 v = *reinterpret_cast<const float4*>(src);
  ushort4 o = { f2bf(v.x), f2bf(v.y), f2bf(v.z), f2bf(v.w) };
  reinterpret_cast<ushort4*>(Wc)[i] = o;
}

// ------- prep_meta: meta[b][k][t] = (u16 row) | (fp16 w)<<16, k-major ------
__global__ __launch_bounds__(256) void prep_meta(const void* __restrict__ idx,
                                                 const float* __restrict__ w,
                                                 uint* __restrict__ meta,
                                                 const int* __restrict__ flag) {
  int i = blockIdx.x * 256 + threadIdx.x;      // i = b*4096 + t
  int b = i >> 12, t = i & 4095;
  int is32 = *flag;
  const int*       i32 = (const int*)idx + (size_t)i * Kk;
  const long long* i64 = (const long long*)idx + (size_t)i * Kk;
  const float*     wp  = w + (size_t)i * Kk;
  uint* mb = meta + ((size_t)b << 17);         // 32*4096 per batch
  #pragma unroll
  for (int k = 0; k < Kk; ++k) {
    uint r = (uint)(is32 ? i32[k] : (int)i64[k]) & 0xFFFFu;
    ushort hw = __half_as_ushort(__float2half(wp[k]));
    mb[(size_t)k * 4096 + t] = r | ((uint)hw << 16);
  }
}

// ---------------- gemm1: [hs|hn] = h @ Wcat^T, fp16 out (R12-proven) -------
__global__ __launch_bounds__(512, 4) void gemm1(const float* __restrict__ h,
                                                const ushort* __restrict__ Wc,
                                                __half* __restrict__ hs,
                                                __half* __restrict__ hn) {
  __shared__ ushort lA[2][64 * 64];    // 2 x 8 KB
  __shared__ ushort lB[2][256 * 64];   // 2 x 32 KB
  const int tid = threadIdx.x, wid = tid >> 6, lane = tid & 63;
  const int wr = wid >> 1, wc = wid & 1;

  const int blk = blockIdx.x;
  const int b = blk & 7, t = blk >> 3;
  const int nblk = t & 1, mblk = t >> 1;
  const int m0 = b * Nn + mblk * 64;
  const ushort* Wbase = Wc + (size_t)nblk * 256 * 256;

  f32x4 acc[8];
  #pragma unroll
  for (int j = 0; j < 8; ++j) acc[j] = f32x4{0.f, 0.f, 0.f, 0.f};

  float4 a0, a1;
  const int ar = tid >> 3, as = tid & 7;             // A stage: row, slot
  auto aload = [&](int kt) {
    const float* src = h + (size_t)(m0 + ar) * 256 + kt * 64 + as * 8;
    a0 = *reinterpret_cast<const float4*>(src);
    a1 = *reinterpret_cast<const float4*>(src + 4);
  };
  auto awrite = [&](int buf) {
    s16x8 u = { (short)f2bf(a0.x), (short)f2bf(a0.y), (short)f2bf(a0.z),
                (short)f2bf(a0.w), (short)f2bf(a1.x), (short)f2bf(a1.y),
                (short)f2bf(a1.z), (short)f2bf(a1.w) };
    *reinterpret_cast<s16x8*>(&lA[buf][ar * 64 + ((as ^ (ar & 7)) << 3)]) = u;
  };
  auto bstage = [&](int buf, int kt) {
    #pragma unroll
    for (int c = 0; c < 4; ++c) {
      int ch = wid + c * 8;
      int r = ch * 8 + (lane >> 3);
      int s = (lane & 7) ^ (r & 7);
      gl_lds16(Wbase + (size_t)r * 256 + kt * 64 + s * 8, &lB[buf][ch * 512]);
    }
  };

  aload(0);
  bstage(0, 0);
  awrite(0);
  __syncthreads();

  int buf = 0;
  for (int kt = 0; kt < 4; ++kt) {
    if (kt < 3) { aload(kt + 1); bstage(buf ^ 1, kt + 1); }
    #pragma unroll
    for (int kk = 0; kk < 2; ++kk) {
      const int ks = kk * 4 + (lane >> 4);
      const int ra = wr * 16 + (lane & 15);
      s16x8 af = *reinterpret_cast<const s16x8*>(
          &lA[buf][ra * 64 + ((ks ^ (ra & 7)) << 3)]);
      s16x8 bfr[8];
      #pragma unroll
      for (int nj = 0; nj < 8; ++nj) {
        int rb = wc * 128 + nj * 16 + (lane & 15);
        bfr[nj] = *reinterpret_cast<const s16x8*>(
            &lB[buf][rb * 64 + ((ks ^ (rb & 7)) << 3)]);
      }
      #pragma unroll
      for (int nj = 0; nj < 8; ++nj)
        acc[nj] = __builtin_amdgcn_mfma_f32_16x16x32_bf16(af, bfr[nj],
                                                          acc[nj], 0, 0, 0);
    }
    if (kt < 3) awrite(buf ^ 1);
    __syncthreads();
    buf ^= 1;
  }

  __half* dst = (nblk == 0) ? hs : hn;
  #pragma unroll
  for (int nj = 0; nj < 8; ++nj)
    #pragma unroll
    for (int jj = 0; jj < 4; ++jj) {
      int row = wr * 16 + (lane >> 4) * 4 + jj;
      int col = wc * 128 + nj * 16 + (lane & 15);
      dst[(size_t)(m0 + row) * 256 + col] = __float2half(acc[nj][jj]);
    }
}

// ---------------- k2a: LDS-staged slice gather (16 waves/CU) ----------------
// Block = (batch b, slice c of 8 fp16 cols), 1024 threads. Stage all 4096 rows
// x 16B of the slice into 64KB LDS via global_load_lds, then each lane gathers
// its target's 32 neighbors from LDS. R13 structure; single change: 512->1024
// threads (16 waves/CU vs 8) to overlap the random ds_read_b128 latency.
// In-place write over hn is safe: one block owns slice (b,c); all hn reads of
// this slice happen in staging before the barrier.
__global__ __launch_bounds__(1024, 1) void k2a(__half* __restrict__ hn,
                                               const uint* __restrict__ meta) {
  __shared__ __align__(16) __half sl[4096 * 8];   // 64 KB
  const int tid = threadIdx.x, wv = tid >> 6, lane = tid & 63;
  const int b = blockIdx.x & 7;
  const int c = blockIdx.x >> 3;                  // slice 0..31
  __half* hnb = hn + ((size_t)b << 20);           // b*4096*256

  // stage: 4 iters x 1024 threads, 16B per lane, linear LDS
  #pragma unroll
  for (int j = 0; j < 4; ++j) {
    int rbase = j * 1024 + wv * 64;               // wave-uniform
    gl_lds16((const ushort*)(hnb + (size_t)(rbase + lane) * 256 + c * 8),
             (ushort*)&sl[rbase * 8]);
  }
  __syncthreads();                                // drains global_load_lds

  const uint* mb = meta + ((size_t)b << 17);

  // each wave: 256 targets in 4 chunks of 64 (lane = target)
  for (int ch = 0; ch < 4; ++ch) {
    const int t = wv * 256 + ch * 64 + lane;
    const uint* mcol = mb + t;

    uint mk[32];                                  // all metadata upfront
    #pragma unroll
    for (int k = 0; k < 32; ++k) mk[k] = mcol[(size_t)k << 12];

    f32x4 aA0{0,0,0,0}, aA1{0,0,0,0}, aB0{0,0,0,0}, aB1{0,0,0,0};

#define DS(k) (*reinterpret_cast<const H2x4*>(&sl[(mk[k] & 0xFFFFu) * 8]))
#define WVAL(k) __half2float(__ushort_as_half((ushort)(mk[k] >> 16)))
#define CONS(b0, b1, q, wt) { \
    b0[0] += (float)q.a.x * wt; b0[1] += (float)q.a.y * wt; \
    b0[2] += (float)q.b.x * wt; b0[3] += (float)q.b.y * wt; \
    b1[0] += (float)q.c.x * wt; b1[1] += (float)q.c.y * wt; \
    b1[2] += (float)q.d.x * wt; b1[3] += (float)q.d.y * wt; }

    H2x4 p0 = DS(0), p1 = DS(1), p2 = DS(2), p3 = DS(3);
    #pragma unroll
    for (int k = 0; k < 32; k += 4) {
      float w0 = WVAL(k), w1 = WVAL(k + 1), w2 = WVAL(k + 2), w3 = WVAL(k + 3);
      H2x4 q0 = p0, q1 = p1, q2 = p2, q3 = p3;
      if (k + 4 < 32) {
        p0 = DS(k + 4); p1 = DS(k + 5); p2 = DS(k + 6); p3 = DS(k + 7);
      }
      CONS(aA0, aA1, q0, w0); CONS(aB0, aB1, q1, w1);
      CONS(aA0, aA1, q2, w2); CONS(aB0, aB1, q3, w3);
    }
#undef DS
#undef WVAL
#undef CONS

    H2x4 o;
    o.a = __floats2half2_rn(aA0[0] + aB0[0], aA0[1] + aB0[1]);
    o.b = __floats2half2_rn(aA0[2] + aB0[2], aA0[3] + aB0[3]);
    o.c = __floats2half2_rn(aA1[0] + aB1[0], aA1[1] + aB1[1]);
    o.d = __floats2half2_rn(aA1[2] + aB1[2], aA1[3] + aB1[3]);
    *reinterpret_cast<H2x4*>(hnb + (size_t)t * 256 + c * 8) = o;  // in-place
  }
}

// ---------------- k2b: out = LN(gelu(hs[m] + hagg[m])) — pure streaming ----
__global__ __launch_bounds__(256) void k2b(const __half* __restrict__ hs,
                                           const __half* __restrict__ hagg,
                                           const float* __restrict__ gamma,
                                           const float* __restrict__ beta,
                                           float* __restrict__ out) {
  const int tid = threadIdx.x, l5 = tid & 31;
  const int m = blockIdx.x * 8 + (tid >> 5);

  H2x4 av = *reinterpret_cast<const H2x4*>(hagg + (size_t)m * Hh + l5 * 8);
  H2x4 sv_ = *reinterpret_cast<const H2x4*>(hs + (size_t)m * Hh + l5 * 8);
  float4 gm0 = reinterpret_cast<const float4*>(gamma)[l5 * 2];
  float4 gm1 = reinterpret_cast<const float4*>(gamma)[l5 * 2 + 1];
  float4 bt0 = reinterpret_cast<const float4*>(beta)[l5 * 2];
  float4 bt1 = reinterpret_cast<const float4*>(beta)[l5 * 2 + 1];

  float g[8];
  g[0] = gelu_t((float)av.a.x + (float)sv_.a.x);
  g[1] = gelu_t((float)av.a.y + (float)sv_.a.y);
  g[2] = gelu_t((float)av.b.x + (float)sv_.b.x);
  g[3] = gelu_t((float)av.b.y + (float)sv_.b.y);
  g[4] = gelu_t((float)av.c.x + (float)sv_.c.x);
  g[5] = gelu_t((float)av.c.y + (float)sv_.c.y);
  g[6] = gelu_t((float)av.d.x + (float)sv_.d.x);
  g[7] = gelu_t((float)av.d.y + (float)sv_.d.y);

  float sv = 0.f, qv = 0.f;
  #pragma unroll
  for (int j = 0; j < 8; ++j) { sv += g[j]; qv += g[j] * g[j]; }
  #pragma unroll
  for (int msk = 16; msk >= 1; msk >>= 1) {   // reduce within 32-lane half
    sv += __shfl_xor(sv, msk, 64);
    qv += __shfl_xor(qv, msk, 64);
  }
  float mean = sv * (1.0f / 256.0f);
  float var  = qv * (1.0f / 256.0f) - mean * mean;
  float inv  = rsqrtf(var + 1e-5f);

  float4 o0, o1;
  o0.x = (g[0] - mean) * inv * gm0.x + bt0.x;
  o0.y = (g[1] - mean) * inv * gm0.y + bt0.y;
  o0.z = (g[2] - mean) * inv * gm0.z + bt0.z;
  o0.w = (g[3] - mean) * inv * gm0.w + bt0.w;
  o1.x = (g[4] - mean) * inv * gm1.x + bt1.x;
  o1.y = (g[5] - mean) * inv * gm1.y + bt1.y;
  o1.z = (g[6] - mean) * inv * gm1.z + bt1.z;
  o1.w = (g[7] - mean) * inv * gm1.w + bt1.w;
  float4* op = reinterpret_cast<float4*>(out + (size_t)m * Hh + l5 * 8);
  op[0] = o0;
  op[1] = o1;
}

extern "C" void kernel_launch(void* const* d_in, const int* in_sizes, int n_in,
                              void* d_out, int out_size, void* d_ws, size_t ws_size,
                              hipStream_t stream) {
  const float* h     = (const float*)d_in[0];
  const void*  idx   = d_in[1];
  const float* w     = (const float*)d_in[2];
  const float* Ws    = (const float*)d_in[3];
  const float* Wn    = (const float*)d_in[4];
  const float* gamma = (const float*)d_in[5];
  const float* beta  = (const float*)d_in[6];
  float* out = (float*)d_out;

  __half* hs = (__half*)d_ws;                       // 16 MB
  __half* hn = hs + (size_t)Mm * Hh;                // 16 MB (becomes hagg)
  ushort* Wc = (ushort*)(hn + (size_t)Mm * Hh);     // 256 KB
  int* flag  = (int*)(Wc + 512 * 256);
  uint* meta = (uint*)(flag + 64);                  // 4 MB

  prep_w<<<128, 256, 0, stream>>>(Ws, Wn, Wc, (const int*)idx, flag);
  prep_meta<<<128, 256, 0, stream>>>(idx, w, meta, flag);
  gemm1<<<1024, 512, 0, stream>>>(h, Wc, hs, hn);
  k2a<<<256, 1024, 0, stream>>>(hn, meta);
  k2b<<<4096, 256, 0, stream>>>(hs, hn, gamma, beta, out);
}

// Round 15
// 58.044 us; speedup vs baseline: 1.4218x; 1.3896x over previous
//
#include <hip/hip_runtime.h>
#include <hip/hip_bf16.h>
#include <hip/hip_fp16.h>
#include <math.h>
#include <stdint.h>

constexpr int Nn = 4096, Kk = 32, Hh = 256;
constexpr int Mm = 8 * Nn;          // 32768 rows

typedef float  f32x4 __attribute__((ext_vector_type(4)));
typedef short  s16x8 __attribute__((ext_vector_type(8)));
struct alignas(16) H2x4 { __half2 a, b, c, d; };   // 8 halfs = 16 B

static __device__ __forceinline__ ushort f2bf(float f) {
  uint32_t u = __float_as_uint(f);
  u += 0x7FFF + ((u >> 16) & 1);
  return (ushort)(u >> 16);
}
static __device__ __forceinline__ void gl_lds16(const ushort* g, ushort* l) {
  __builtin_amdgcn_global_load_lds(
      (const __attribute__((address_space(1))) void*)g,
      (__attribute__((address_space(3))) void*)l, 16, 0, 0);
}
// gelu(x) ~= x - x/(e^y + 1),  y = x*(2c + 2c*0.044715*x^2), c = 0.79788456
static __device__ __forceinline__ float gelu_t(float x) {
  float u = x * x;
  float y = x * (1.5957691216f + 0.0713548162726f * u);
  float t = __expf(y);
  return x - x * __builtin_amdgcn_rcpf(t + 1.0f);
}

// ------- prep: Wcat = [Ws; Wn] bf16 [512][256]; also idx-dtype detect ------
__global__ __launch_bounds__(256) void prep_w(const float* __restrict__ Ws,
                                              const float* __restrict__ Wn,
                                              ushort* __restrict__ Wc,
                                              const int* __restrict__ idxp,
                                              int* __restrict__ flag) {
  if (blockIdx.x == 0 && threadIdx.x < 64) {   // wave 0: int64 high-word test
    unsigned long long bl = __ballot(idxp[2 * threadIdx.x + 1] != 0);
    if (threadIdx.x == 0) *flag = (bl != 0ULL) ? 1 : 0;  // 1=int32, 0=int64
  }
  int i = blockIdx.x * 256 + threadIdx.x;      // 32768 threads, 4 elems each
  int j  = i >> 6;
  int k4 = i & 63;
  const float* src = (j < 256) ? (Ws + (size_t)j * 256 + k4 * 4)
                               : (Wn + (size_t)(j - 256) * 256 + k4 * 4);
  float4 v = *reinterpret_cast<const float4*>(src);
  ushort4 o = { f2bf(v.x), f2bf(v.y), f2bf(v.z), f2bf(v.w) };
  reinterpret_cast<ushort4*>(Wc)[i] = o;
}

// ---------------- gemm1: [hs|hn] = h @ Wcat^T, fp16 out, no epilogue -------
__global__ __launch_bounds__(512, 4) void gemm1(const float* __restrict__ h,
                                                const ushort* __restrict__ Wc,
                                                __half* __restrict__ hs,
                                                __half* __restrict__ hn) {
  __shared__ ushort lA[2][64 * 64];    // 2 x 8 KB
  __shared__ ushort lB[2][256 * 64];   // 2 x 32 KB
  const int tid = threadIdx.x, wid = tid >> 6, lane = tid & 63;
  const int wr = wid >> 1, wc = wid & 1;

  const int blk = blockIdx.x;
  const int b = blk & 7, t = blk >> 3;
  const int nblk = t & 1, mblk = t >> 1;
  const int m0 = b * Nn + mblk * 64;
  const ushort* Wbase = Wc + (size_t)nblk * 256 * 256;

  f32x4 acc[8];
  #pragma unroll
  for (int j = 0; j < 8; ++j) acc[j] = f32x4{0.f, 0.f, 0.f, 0.f};

  float4 a0, a1;
  const int ar = tid >> 3, as = tid & 7;             // A stage: row, slot
  auto aload = [&](int kt) {
    const float* src = h + (size_t)(m0 + ar) * 256 + kt * 64 + as * 8;
    a0 = *reinterpret_cast<const float4*>(src);
    a1 = *reinterpret_cast<const float4*>(src + 4);
  };
  auto awrite = [&](int buf) {
    s16x8 u = { (short)f2bf(a0.x), (short)f2bf(a0.y), (short)f2bf(a0.z),
                (short)f2bf(a0.w), (short)f2bf(a1.x), (short)f2bf(a1.y),
                (short)f2bf(a1.z), (short)f2bf(a1.w) };
    *reinterpret_cast<s16x8*>(&lA[buf][ar * 64 + ((as ^ (ar & 7)) << 3)]) = u;
  };
  auto bstage = [&](int buf, int kt) {
    #pragma unroll
    for (int c = 0; c < 4; ++c) {
      int ch = wid + c * 8;
      int r = ch * 8 + (lane >> 3);
      int s = (lane & 7) ^ (r & 7);
      gl_lds16(Wbase + (size_t)r * 256 + kt * 64 + s * 8, &lB[buf][ch * 512]);
    }
  };

  aload(0);
  bstage(0, 0);
  awrite(0);
  __syncthreads();

  int buf = 0;
  for (int kt = 0; kt < 4; ++kt) {
    if (kt < 3) { aload(kt + 1); bstage(buf ^ 1, kt + 1); }
    #pragma unroll
    for (int kk = 0; kk < 2; ++kk) {
      const int ks = kk * 4 + (lane >> 4);
      const int ra = wr * 16 + (lane & 15);
      s16x8 af = *reinterpret_cast<const s16x8*>(
          &lA[buf][ra * 64 + ((ks ^ (ra & 7)) << 3)]);
      s16x8 bfr[8];
      #pragma unroll
      for (int nj = 0; nj < 8; ++nj) {
        int rb = wc * 128 + nj * 16 + (lane & 15);
        bfr[nj] = *reinterpret_cast<const s16x8*>(
            &lB[buf][rb * 64 + ((ks ^ (rb & 7)) << 3)]);
      }
      #pragma unroll
      for (int nj = 0; nj < 8; ++nj)
        acc[nj] = __builtin_amdgcn_mfma_f32_16x16x32_bf16(af, bfr[nj],
                                                          acc[nj], 0, 0, 0);
    }
    if (kt < 3) awrite(buf ^ 1);
    __syncthreads();
    buf ^= 1;
  }

  __half* dst = (nblk == 0) ? hs : hn;
  #pragma unroll
  for (int nj = 0; nj < 8; ++nj)
    #pragma unroll
    for (int jj = 0; jj < 4; ++jj) {
      int row = wr * 16 + (lane >> 4) * 4 + jj;
      int col = wc * 128 + nj * 16 + (lane & 15);
      dst[(size_t)(m0 + row) * 256 + col] = __float2half(acc[nj][jj]);
    }
}

// ---------------- k2: out = LN(gelu(hs[m] + sum_k w * hn[idx_k])) ----------
// R12-proven: one row/wave, k-split halves, grid 8192x256, &7 map, depth-4
// named prefetch, dual f32 acc banks; hs/hn fp16 consumed via v_fma_mix.
// Measured wall: gather at ~0.64 L2-lines/cyc/CU (~72% of per-CU L2 port).
__global__ __launch_bounds__(256, 4) void k2(const __half* __restrict__ hs,
                                             const __half* __restrict__ hn,
                                             const void* __restrict__ idx,
                                             const float* __restrict__ w,
                                             const float* __restrict__ gamma,
                                             const float* __restrict__ beta,
                                             float* __restrict__ out,
                                             const int* __restrict__ flag) {
  const int tid = threadIdx.x, wv = tid >> 6, lane = tid & 63;
  const int hw = lane >> 5, l5 = lane & 31;
  const int b = blockIdx.x & 7;                       // batch -> XCD pin
  const int m = b * Nn + (blockIdx.x >> 3) * 4 + wv;  // 4 rows/block, 1/wave
  const int is32 = *flag;

  // lane l5 (mod 16) of half hw owns idx/w[k = hw*16 + (l5&15)]
  size_t kb = (size_t)m * Kk + hw * 16 + (l5 & 15);
  int   myi = is32 ? ((const int*)idx)[kb] : (int)((const long long*)idx)[kb];
  float myw = w[kb];

  // early long-latency loads (consumed only in the epilogue)
  H2x4 hvq = *reinterpret_cast<const H2x4*>(hs + (size_t)m * Hh + l5 * 8);
  float4 gm0 = reinterpret_cast<const float4*>(gamma)[l5 * 2];
  float4 gm1 = reinterpret_cast<const float4*>(gamma)[l5 * 2 + 1];
  float4 bt0 = reinterpret_cast<const float4*>(beta)[l5 * 2];
  float4 bt1 = reinterpret_cast<const float4*>(beta)[l5 * 2 + 1];

  const __half* hnb = hn + (size_t)b * Nn * Hh;

  auto ld = [&](int k) -> H2x4 {         // k in 0..15 within this half
    int r = __shfl(myi, k, 32);
    return *reinterpret_cast<const H2x4*>(hnb + ((size_t)r << 8) + (l5 << 3));
  };

  f32x4 aA0{0,0,0,0}, aA1{0,0,0,0}, aB0{0,0,0,0}, aB1{0,0,0,0};

#define CONS(b0, b1, q, wt) { \
    b0[0] += (float)q.a.x * wt; b0[1] += (float)q.a.y * wt; \
    b0[2] += (float)q.b.x * wt; b0[3] += (float)q.b.y * wt; \
    b1[0] += (float)q.c.x * wt; b1[1] += (float)q.c.y * wt; \
    b1[2] += (float)q.d.x * wt; b1[3] += (float)q.d.y * wt; }

  H2x4 p0 = ld(0), p1 = ld(1), p2 = ld(2), p3 = ld(3);

  #pragma unroll
  for (int k = 0; k < 16; k += 4) {
    float w0 = __shfl(myw, k, 32),     w1 = __shfl(myw, k + 1, 32);
    float w2 = __shfl(myw, k + 2, 32), w3 = __shfl(myw, k + 3, 32);
    H2x4 q0 = p0, q1 = p1, q2 = p2, q3 = p3;
    if (k + 4 < 16) {
      p0 = ld(k + 4); p1 = ld(k + 5); p2 = ld(k + 6); p3 = ld(k + 7);
    }
    CONS(aA0, aA1, q0, w0); CONS(aB0, aB1, q1, w1);
    CONS(aA0, aA1, q2, w2); CONS(aB0, aB1, q3, w3);
  }
#undef CONS

  // merge dual banks, then merge the two k-halves across lane^32
  float g[8];
  #pragma unroll
  for (int j = 0; j < 4; ++j) {
    g[j]     = aA0[j] + aB0[j];
    g[j + 4] = aA1[j] + aB1[j];
  }
  #pragma unroll
  for (int j = 0; j < 8; ++j)
    g[j] += __shfl_xor(g[j], 32, 64);

  // add self term, GELU (both halves compute identically from here)
  g[0] = gelu_t(g[0] + (float)hvq.a.x);
  g[1] = gelu_t(g[1] + (float)hvq.a.y);
  g[2] = gelu_t(g[2] + (float)hvq.b.x);
  g[3] = gelu_t(g[3] + (float)hvq.b.y);
  g[4] = gelu_t(g[4] + (float)hvq.c.x);
  g[5] = gelu_t(g[5] + (float)hvq.c.y);
  g[6] = gelu_t(g[6] + (float)hvq.d.x);
  g[7] = gelu_t(g[7] + (float)hvq.d.y);

  float sv = 0.f, qv = 0.f;
  #pragma unroll
  for (int j = 0; j < 8; ++j) { sv += g[j]; qv += g[j] * g[j]; }
  #pragma unroll
  for (int msk = 16; msk >= 1; msk >>= 1) {   // reduce within each 32-lane half
    sv += __shfl_xor(sv, msk, 64);
    qv += __shfl_xor(qv, msk, 64);
  }
  float mean = sv * (1.0f / 256.0f);
  float var  = qv * (1.0f / 256.0f) - mean * mean;
  float inv  = rsqrtf(var + 1e-5f);

  float4 o0, o1;
  o0.x = (g[0] - mean) * inv * gm0.x + bt0.x;
  o0.y = (g[1] - mean) * inv * gm0.y + bt0.y;
  o0.z = (g[2] - mean) * inv * gm0.z + bt0.z;
  o0.w = (g[3] - mean) * inv * gm0.w + bt0.w;
  o1.x = (g[4] - mean) * inv * gm1.x + bt1.x;
  o1.y = (g[5] - mean) * inv * gm1.y + bt1.y;
  o1.z = (g[6] - mean) * inv * gm1.z + bt1.z;
  o1.w = (g[7] - mean) * inv * gm1.w + bt1.w;
  if (hw == 0) {                               // one half writes the row
    float4* op = reinterpret_cast<float4*>(out + (size_t)m * Hh + l5 * 8);
    op[0] = o0;
    op[1] = o1;
  }
}

extern "C" void kernel_launch(void* const* d_in, const int* in_sizes, int n_in,
                              void* d_out, int out_size, void* d_ws, size_t ws_size,
                              hipStream_t stream) {
  const float* h     = (const float*)d_in[0];
  const void*  idx   = d_in[1];
  const float* w     = (const float*)d_in[2];
  const float* Ws    = (const float*)d_in[3];
  const float* Wn    = (const float*)d_in[4];
  const float* gamma = (const float*)d_in[5];
  const float* beta  = (const float*)d_in[6];
  float* out = (float*)d_out;

  __half* hs = (__half*)d_ws;                       // 16 MB
  __half* hn = hs + (size_t)Mm * Hh;                // 16 MB
  ushort* Wc = (ushort*)(hn + (size_t)Mm * Hh);     // 256 KB
  int* flag  = (int*)(Wc + 512 * 256);

  prep_w<<<128, 256, 0, stream>>>(Ws, Wn, Wc, (const int*)idx, flag);
  gemm1<<<1024, 512, 0, stream>>>(h, Wc, hs, hn);
  k2<<<8192, 256, 0, stream>>>(hs, hn, idx, w, gamma, beta, out, flag);
}